// Round 8
// baseline (913.909 us; speedup 1.0000x reference)
//
#include <hip/hip_runtime.h>

// Attention_11845519803093 — R8: attn v6 — K-parallel waves, barrier-free K-loop.
//   * fixed-m softmax => O/bins are pure sums => waves split K (tiles w, w+4, w+8)
//   * K/Q/E MFMA fragments loaded straight from global (fp32->fp16 pack in regs)
//   * V transposed via wave-private LDS; P round-trip wave-private (lgkmcnt only)
//   * grid 37x192 = 7104 blocks of 16 q-rows; combine = one LDS reduction
//   * GEMMs unchanged (split-fp16 MFMA)
// ws layout: q | k | v | ao | M1 | M2

#define BB    16
#define NNq   577
#define DIMM  768
#define NHh   12
#define HD    64
#define MM    9232

typedef _Float16 h8 __attribute__((ext_vector_type(8)));
typedef float    f4 __attribute__((ext_vector_type(4)));

__device__ inline h8 pack8(float4 a, float4 b) {
    h8 r;
    r[0]=(_Float16)a.x; r[1]=(_Float16)a.y; r[2]=(_Float16)a.z; r[3]=(_Float16)a.w;
    r[4]=(_Float16)b.x; r[5]=(_Float16)b.y; r[6]=(_Float16)b.z; r[7]=(_Float16)b.w;
    return r;
}

// ---------------------------------------------------------------- mask tables
__global__ void mask_init(_Float16* __restrict__ M1g, _Float16* __restrict__ M2g)
{
    const int id = blockIdx.x*256 + threadIdx.x;     // 640*64
    if (id >= 640*64) return;
    const int key = id >> 6, bin = id & 63;
    int vb = 255, hb = 255;
    if (key == 0)      { vb = 24; hb = 49; }
    else if (key < NNq){ const int kq = key-1, kv = kq/24; vb = kv; hb = 25 + (kq - kv*24); }
    M1g[id] = (bin==vb || bin==hb) ? (_Float16)1.f : (_Float16)0.f;
    M2g[bin*640 + key] =
        ((key < NNq) && (bin==vb || bin==hb || bin==50)) ? (_Float16)1.f : (_Float16)0.f;
}

// ---------------------------------------------------------------- split-fp16 MFMA GEMM core
template <typename F>
__device__ __forceinline__ void gemm128(const float* __restrict__ Amat,
                                        const float* __restrict__ Bmat,
                                        F epi)
{
    __shared__ _Float16 Ah[128][40], Al[128][40], Bh[128][40], Bl[128][40];
    const int t  = threadIdx.x;
    const int wv = t >> 6, lane = t & 63, lo = lane & 15, g = lane >> 4;
    const int wm = (wv >> 1) << 6, wn = (wv & 1) << 6;
    const int bm = blockIdx.y << 7, bn = blockIdx.x << 7;
    f4 acc[4][4] = {};
    const int lr = t >> 1;
    const int lc = (t & 1) << 4;
    const int am = bm + lr;
    const bool aok = am < MM;
    const float* arow = Amat + (size_t)(aok ? am : 0) * DIMM + lc;
    const float* brow = Bmat + (size_t)(bn + lr) * DIMM + lc;

    for (int k0 = 0; k0 < DIMM; k0 += 32) {
        float4 a0 = make_float4(0,0,0,0), a1 = a0, a2 = a0, a3 = a0;
        if (aok) {
            a0 = *(const float4*)(arow + k0);      a1 = *(const float4*)(arow + k0 + 4);
            a2 = *(const float4*)(arow + k0 + 8);  a3 = *(const float4*)(arow + k0 + 12);
        }
        const float4 b0 = *(const float4*)(brow + k0);
        const float4 b1 = *(const float4*)(brow + k0 + 4);
        const float4 b2 = *(const float4*)(brow + k0 + 8);
        const float4 b3 = *(const float4*)(brow + k0 + 12);
        __syncthreads();
        {
            const h8 ah0 = pack8(a0, a1), ah1 = pack8(a2, a3);
            float4 r0, r1, r2, r3;
            r0.x=a0.x-(float)ah0[0]; r0.y=a0.y-(float)ah0[1]; r0.z=a0.z-(float)ah0[2]; r0.w=a0.w-(float)ah0[3];
            r1.x=a1.x-(float)ah0[4]; r1.y=a1.y-(float)ah0[5]; r1.z=a1.z-(float)ah0[6]; r1.w=a1.w-(float)ah0[7];
            r2.x=a2.x-(float)ah1[0]; r2.y=a2.y-(float)ah1[1]; r2.z=a2.z-(float)ah1[2]; r2.w=a2.w-(float)ah1[3];
            r3.x=a3.x-(float)ah1[4]; r3.y=a3.y-(float)ah1[5]; r3.z=a3.z-(float)ah1[6]; r3.w=a3.w-(float)ah1[7];
            *(h8*)&Ah[lr][lc]   = ah0;  *(h8*)&Ah[lr][lc+8] = ah1;
            *(h8*)&Al[lr][lc]   = pack8(r0, r1);
            *(h8*)&Al[lr][lc+8] = pack8(r2, r3);
        }
        {
            const h8 bh0 = pack8(b0, b1), bh1 = pack8(b2, b3);
            float4 r0, r1, r2, r3;
            r0.x=b0.x-(float)bh0[0]; r0.y=b0.y-(float)bh0[1]; r0.z=b0.z-(float)bh0[2]; r0.w=b0.w-(float)bh0[3];
            r1.x=b1.x-(float)bh0[4]; r1.y=b1.y-(float)bh0[5]; r1.z=b1.z-(float)bh0[6]; r1.w=b1.w-(float)bh0[7];
            r2.x=b2.x-(float)bh1[0]; r2.y=b2.y-(float)bh1[1]; r2.z=b2.z-(float)bh1[2]; r2.w=b2.w-(float)bh1[3];
            r3.x=b3.x-(float)bh1[4]; r3.y=b3.y-(float)bh1[5]; r3.z=b3.z-(float)bh1[6]; r3.w=b3.w-(float)bh1[7];
            *(h8*)&Bh[lr][lc]   = bh0;  *(h8*)&Bh[lr][lc+8] = bh1;
            *(h8*)&Bl[lr][lc]   = pack8(r0, r1);
            *(h8*)&Bl[lr][lc+8] = pack8(r2, r3);
        }
        __syncthreads();
        h8 fah[4], fal[4], fbh[4], fbl[4];
        #pragma unroll
        for (int i = 0; i < 4; ++i) {
            fah[i] = *(const h8*)&Ah[wm + 16*i + lo][g<<3];
            fal[i] = *(const h8*)&Al[wm + 16*i + lo][g<<3];
            fbh[i] = *(const h8*)&Bh[wn + 16*i + lo][g<<3];
            fbl[i] = *(const h8*)&Bl[wn + 16*i + lo][g<<3];
        }
        #pragma unroll
        for (int mi = 0; mi < 4; ++mi) {
            #pragma unroll
            for (int ni = 0; ni < 4; ++ni) {
                acc[mi][ni] = __builtin_amdgcn_mfma_f32_16x16x32_f16(fah[mi], fbh[ni], acc[mi][ni], 0, 0, 0);
                acc[mi][ni] = __builtin_amdgcn_mfma_f32_16x16x32_f16(fah[mi], fbl[ni], acc[mi][ni], 0, 0, 0);
                acc[mi][ni] = __builtin_amdgcn_mfma_f32_16x16x32_f16(fal[mi], fbh[ni], acc[mi][ni], 0, 0, 0);
            }
        }
    }
    epi(acc, bm, bn, wm, wn, lo, g);
}

// ---------------------------------------------------------------- QKV GEMM (MFMA)
__global__ __launch_bounds__(256, 2)
void qkv_gemm(const float* __restrict__ x, const float* __restrict__ w,
              float* __restrict__ q, float* __restrict__ k, float* __restrict__ v)
{
    gemm128(x, w, [=](f4 (&acc)[4][4], int bm, int bn, int wm, int wn, int lo, int g) {
        const int three = bn / 768;
        const int cb    = bn - three * 768;
        float* dst = (three == 0) ? q : ((three == 1) ? k : v);
        const float sc = (three == 0) ? 0.125f : 1.0f;
        #pragma unroll
        for (int mi = 0; mi < 4; ++mi) {
            #pragma unroll
            for (int reg = 0; reg < 4; ++reg) {
                const int m = bm + wm + 16*mi + 4*g + reg;
                if (m >= MM) continue;
                const int b_ = m / NNq;
                const int n_ = m - b_ * NNq;
                #pragma unroll
                for (int ni = 0; ni < 4; ++ni) {
                    const int n  = cb + wn + 16*ni + lo;
                    const int hh = n >> 6;
                    const int d  = n & 63;
                    dst[(((size_t)(b_*NHh + hh)*NNq + n_) << 6) + d] = acc[mi][ni][reg] * sc;
                }
            }
        }
    });
}

// ---------------------------------------------------------------- proj GEMM (MFMA)
__global__ __launch_bounds__(256, 2)
void proj_gemm(const float* __restrict__ A, const float* __restrict__ w,
               const float* __restrict__ bias, float* __restrict__ out)
{
    gemm128(A, w, [=](f4 (&acc)[4][4], int bm, int bn, int wm, int wn, int lo, int g) {
        #pragma unroll
        for (int ni = 0; ni < 4; ++ni) {
            const int n  = bn + wn + 16*ni + lo;
            const float bb = bias[n];
            #pragma unroll
            for (int mi = 0; mi < 4; ++mi) {
                #pragma unroll
                for (int reg = 0; reg < 4; ++reg) {
                    const int m = bm + wm + 16*mi + 4*g + reg;
                    if (m >= MM) continue;
                    out[(size_t)m*DIMM + n] = acc[mi][ni][reg] + bb;
                }
            }
        }
    });
}

// ---------------------------------------------------------------- fused attention v6
__global__ __launch_bounds__(256, 3)
void attn_fused(const float* __restrict__ qg_, const float* __restrict__ kg_,
                const float* __restrict__ vg_,
                const float* __restrict__ tkv, const float* __restrict__ tkh,
                const float* __restrict__ tvv, const float* __restrict__ tvh,
                const _Float16* __restrict__ M1g, const _Float16* __restrict__ M2g,
                float* __restrict__ ao)
{
    // LDS 48128 B:
    //  [    0,36864) VsT per-wave: w*9216 B, fp16 [64][72]  (V^T for this wave's K-tile)
    //                combine overlay: Ocomb f32 [4][16][64] @0, binsC f32 [4][16][52] @16384
    //  [36864,46080) Pt per-wave: w*2304 B, fp16 [16][72]   (prologue: Pq fp16 [16][64])
    //  [46080,48128) Eb fp16 [16][64]
    __shared__ __align__(16) char smem[48128];
    const int t = threadIdx.x, w = t >> 6, lane = t & 63;
    const int lo = lane & 15, g = lane >> 4, gb = g << 3;
    const int bh = blockIdx.y, qt0 = blockIdx.x * 16;
    const size_t base = (size_t)bh * NNq * HD;

    _Float16* VsT = (_Float16*)(smem + w*9216);
    _Float16* Ptw = (_Float16*)(smem + 36864 + w*2304);
    _Float16* Pq  = (_Float16*)(smem + 36864);
    _Float16* Eb  = (_Float16*)(smem + 46080);

    // ---- qrel[16][60] ----
    for (int e = t; e < 16*60; e += 256) {
        const int qr = e / 60, r = e - qr*60, qgl = qt0 + qr;
        float s = 0.f;
        if (qgl < NNq) {
            const float* qp = qg_ + base + (size_t)qgl*HD;
            const float* tb = (r < 30) ? (tkv + r*HD) : (tkh + (r-30)*HD);
            #pragma unroll
            for (int d = 0; d < HD; d += 4) {
                const float4 a = *(const float4*)(qp + d);
                const float4 b = *(const float4*)(tb + d);
                s += a.x*b.x + a.y*b.y + a.z*b.z + a.w*b.w;
            }
        }
        Pq[qr*64 + r] = (_Float16)s;
    }
    __syncthreads();
    // ---- E[16][64] ----
    for (int e = t; e < 16*64; e += 256) {
        const int q = e >> 6, bin = e & 63, qgl = qt0 + q;
        _Float16 val = (_Float16)0.f;
        if (qgl < NNq && bin < 50) {
            if (qgl == 0) {
                val = (bin <= 24) ? Pq[0] : Pq[30];
            } else {
                const int qq = qgl - 1, qv = qq / 24, qh = qq - qv*24;
                if (bin < 24)      { int dv = bin - qv; dv = min(14, max(-14, dv)); val = Pq[q*64 + dv + 15]; }
                else if (bin == 24)  val = Pq[q*64 + 0];
                else if (bin < 49) { int dh = (bin-25) - qh; dh = min(14, max(-14, dh)); val = Pq[q*64 + 30 + dh + 15]; }
                else                 val = Pq[q*64 + 30];
            }
        }
        Eb[e] = val;
    }
    __syncthreads();

    // ---- invariant fragments (direct global fp32 -> fp16 pack) ----
    const h8 e0 = *(const h8*)&Eb[lo*64 + gb];
    const h8 e1 = *(const h8*)&Eb[lo*64 + 32 + gb];
    h8 a0, a1;
    {
        const float* qp = qg_ + base + (size_t)(qt0 + lo)*HD;
        a0 = pack8(*(const float4*)(qp + gb),      *(const float4*)(qp + gb + 4));
        a1 = pack8(*(const float4*)(qp + 32 + gb), *(const float4*)(qp + 32 + gb + 4));
    }

    f4 o_acc [4] = {f4{0,0,0,0}, f4{0,0,0,0}, f4{0,0,0,0}, f4{0,0,0,0}};
    f4 binacc[4] = {f4{0,0,0,0}, f4{0,0,0,0}, f4{0,0,0,0}, f4{0,0,0,0}};

    // ---- barrier-free K-loop: wave w owns tiles w, w+4, w+8 ----
    for (int kt0 = w*64; kt0 < NNq; kt0 += 256) {
        // stage V^T (wave-private)
        {
            const float* vrow = vg_ + base + (size_t)(kt0 + lane)*HD;
            #pragma unroll
            for (int p = 0; p < 4; ++p) {
                const int d0 = p << 4;
                const float4 v0 = *(const float4*)(vrow + d0);
                const float4 v1 = *(const float4*)(vrow + d0 + 4);
                const float4 v2 = *(const float4*)(vrow + d0 + 8);
                const float4 v3 = *(const float4*)(vrow + d0 + 12);
                const h8 hA = pack8(v0, v1), hB = pack8(v2, v3);
                #pragma unroll
                for (int j = 0; j < 8; ++j) {
                    VsT[(d0 + j)*72 + lane]     = hA[j];
                    VsT[(d0 + 8 + j)*72 + lane] = hB[j];
                }
            }
        }
        // S = Q·K^T + E·M1^T
        f4 Sc[4];
        #pragma unroll
        for (int c = 0; c < 4; ++c) {
            const int key = kt0 + 16*c + lo;
            const float* kp = kg_ + base + (size_t)key*HD;
            const h8 kb0 = pack8(*(const float4*)(kp + gb),      *(const float4*)(kp + gb + 4));
            const h8 kb1 = pack8(*(const float4*)(kp + 32 + gb), *(const float4*)(kp + 32 + gb + 4));
            const h8 m10 = *(const h8*)(M1g + (size_t)key*64 + gb);
            const h8 m11 = *(const h8*)(M1g + (size_t)key*64 + 32 + gb);
            f4 acc = f4{0,0,0,0};
            acc = __builtin_amdgcn_mfma_f32_16x16x32_f16(a0, kb0, acc, 0, 0, 0);
            acc = __builtin_amdgcn_mfma_f32_16x16x32_f16(a1, kb1, acc, 0, 0, 0);
            acc = __builtin_amdgcn_mfma_f32_16x16x32_f16(e0, m10, acc, 0, 0, 0);
            acc = __builtin_amdgcn_mfma_f32_16x16x32_f16(e1, m11, acc, 0, 0, 0);
            Sc[c] = acc;
        }
        // P = exp(S), wave-private Pt round trip
        #pragma unroll
        for (int c = 0; c < 4; ++c) {
            const bool ok = (kt0 + 16*c + lo) < NNq;
            #pragma unroll
            for (int i = 0; i < 4; ++i) {
                const float p = ok ? __expf(Sc[c][i]) : 0.f;
                Ptw[(4*g + i)*72 + 16*c + lo] = (_Float16)p;
            }
        }
        const h8 p0 = *(const h8*)&Ptw[lo*72 + gb];
        const h8 p1 = *(const h8*)&Ptw[lo*72 + 32 + gb];
        // bins += P @ M2^T
        #pragma unroll
        for (int c = 0; c < 4; ++c) {
            const h8 m20 = *(const h8*)(M2g + (size_t)(16*c + lo)*640 + kt0 + gb);
            const h8 m21 = *(const h8*)(M2g + (size_t)(16*c + lo)*640 + kt0 + 32 + gb);
            binacc[c] = __builtin_amdgcn_mfma_f32_16x16x32_f16(p0, m20, binacc[c], 0, 0, 0);
            binacc[c] = __builtin_amdgcn_mfma_f32_16x16x32_f16(p1, m21, binacc[c], 0, 0, 0);
        }
        // O += P @ V
        #pragma unroll
        for (int c = 0; c < 4; ++c) {
            const h8 v0 = *(const h8*)&VsT[(16*c + lo)*72 + gb];
            const h8 v1 = *(const h8*)&VsT[(16*c + lo)*72 + 32 + gb];
            o_acc[c] = __builtin_amdgcn_mfma_f32_16x16x32_f16(p0, v0, o_acc[c], 0, 0, 0);
            o_acc[c] = __builtin_amdgcn_mfma_f32_16x16x32_f16(p1, v1, o_acc[c], 0, 0, 0);
        }
    }

    // ---- combine: 4-way partial sums ----
    __syncthreads();                       // all waves done with VsT/Pt
    float* Ocomb = (float*)smem;           // [4][16][64]
    float* binsC = (float*)(smem + 16384); // [4][16][52]
    #pragma unroll
    for (int c = 0; c < 4; ++c) {
        #pragma unroll
        for (int i = 0; i < 4; ++i)
            Ocomb[(w*16 + 4*g + i)*64 + 16*c + lo] = o_acc[c][i];
        const int bc = 16*c + lo;
        if (bc <= 50) {
            #pragma unroll
            for (int i = 0; i < 4; ++i)
                binsC[(w*16 + 4*g + i)*52 + bc] = binacc[c][i];
        }
    }
    __syncthreads();
    for (int e = t; e < 16*64; e += 256)
        Ocomb[e] = Ocomb[e] + Ocomb[1024 + e] + Ocomb[2048 + e] + Ocomb[3072 + e];
    for (int e = t; e < 16*51; e += 256) {
        const int row = e / 51, bc = e - row*51, idx = row*52 + bc;
        binsC[idx] = binsC[idx] + binsC[832 + idx] + binsC[1664 + idx] + binsC[2496 + idx];
    }
    __syncthreads();

    // ---- epilogue: thread -> (row, 4 d-cols) ----
    {
        const int r = t >> 4, d0 = (t & 15) << 2;
        const int qgl = qt0 + r;
        if (qgl < NNq) {
            const float l = binsC[r*52 + 50];
            const float invl = 1.f / l;
            float o[4] = {Ocomb[r*64 + d0], Ocomb[r*64 + d0 + 1],
                          Ocomb[r*64 + d0 + 2], Ocomb[r*64 + d0 + 3]};
            if (qgl == 0) {
                #pragma unroll
                for (int c = 0; c < 4; ++c) o[c] += l * (tvv[d0 + c] + tvh[d0 + c]);
            } else {
                const int qq = qgl - 1, qv = qq / 24, qh = qq - qv*24;
                for (int bin = 0; bin < 24; ++bin) {
                    const float wq = binsC[r*52 + bin];
                    int dv = bin - qv; dv = min(14, max(-14, dv));
                    const float* tb = tvv + (dv + 15)*HD + d0;
                    #pragma unroll
                    for (int c = 0; c < 4; ++c) o[c] += wq * tb[c];
                }
                {
                    const float wq = binsC[r*52 + 24];
                    #pragma unroll
                    for (int c = 0; c < 4; ++c) o[c] += wq * tvv[d0 + c];
                }
                for (int bin = 0; bin < 24; ++bin) {
                    const float wq = binsC[r*52 + 25 + bin];
                    int dh = bin - qh; dh = min(14, max(-14, dh));
                    const float* tb = tvh + (dh + 15)*HD + d0;
                    #pragma unroll
                    for (int c = 0; c < 4; ++c) o[c] += wq * tb[c];
                }
                {
                    const float wq = binsC[r*52 + 49];
                    #pragma unroll
                    for (int c = 0; c < 4; ++c) o[c] += wq * tvh[d0 + c];
                }
            }
            const int b_ = bh / NHh, h_ = bh - b_*NHh;
            float* dst = ao + (size_t)(b_*NNq + qgl)*DIMM + h_*HD + d0;
            dst[0] = o[0]*invl; dst[1] = o[1]*invl; dst[2] = o[2]*invl; dst[3] = o[3]*invl;
        }
    }
}

// ---------------------------------------------------------------- launcher
extern "C" void kernel_launch(void* const* d_in, const int* in_sizes, int n_in,
                              void* d_out, int out_size, void* d_ws, size_t ws_size,
                              hipStream_t stream)
{
    const float* x      = (const float*)d_in[0];
    const float* qkv_w  = (const float*)d_in[1];
    const float* proj_w = (const float*)d_in[2];
    const float* proj_b = (const float*)d_in[3];
    const float* tkv    = (const float*)d_in[4];
    const float* tkh    = (const float*)d_in[5];
    const float* tvv    = (const float*)d_in[6];
    const float* tvh    = (const float*)d_in[7];
    float* out = (float*)d_out;
    float* ws  = (float*)d_ws;

    const size_t SZ = (size_t)BB * NHh * NNq * HD;   // 7,090,176
    float* q  = ws;
    float* k  = ws + SZ;
    float* v  = ws + 2*SZ;
    float* ao = ws + 3*SZ;
    _Float16* M1g = (_Float16*)(ws + 4*SZ);          // 640*64 fp16
    _Float16* M2g = M1g + 640*64;                    // 64*640 fp16

    dim3 b256(256, 1, 1);
    mask_init<<<160, b256, 0, stream>>>(M1g, M2g);

    dim3 g1(2304/128, (MM + 127)/128, 1);            // 18 x 73
    qkv_gemm<<<g1, b256, 0, stream>>>(x, qkv_w, q, k, v);

    dim3 g2(37, BB*NHh, 1);                          // 37 x 192 = 7104 blocks
    attn_fused<<<g2, b256, 0, stream>>>(q, k, v, tkv, tkh, tvv, tvh, M1g, M2g, ao);

    dim3 g3(DIMM/128, (MM + 127)/128, 1);            // 6 x 73
    proj_gemm<<<g3, b256, 0, stream>>>(ao, proj_w, proj_b, out);
}